// Round 7
// baseline (301.810 us; speedup 1.0000x reference)
//
#include <hip/hip_runtime.h>
#include <hip/hip_cooperative_groups.h>
#include <stdint.h>

namespace cg = cooperative_groups;

#define N_DIM 256
#define C_DIM 64
#define D_DIM 4096
#define NQ    4              // k-split ways (blocks per n)
#define KQB   (D_DIM / NQ)   // 1024 k per block
#define KWV   (KQB / 4)      // 256 k per wave
#define NSTEP (KWV / 16)     // 16 MFMA k-steps per wave
#define SLAB  (N_DIM * C_DIM * C_DIM)   // 1048576 floats per partial slab

// ws layout: uh (f16 u, 512 KB) @0; vh (f16 v, 2 MB) @1MB; part (16 MB) @4MB
#define VH_OFF   (1u << 20)
#define PART_OFF (4u << 20)

typedef __bf16    bf16x8_t __attribute__((ext_vector_type(8)));
typedef _Float16  f16x8_t  __attribute__((ext_vector_type(8)));
typedef float     f32x16_t __attribute__((ext_vector_type(16)));

union Frag {
  uint4     q;
  uint32_t  u[4];
  bf16x8_t  b;
};
union FragH {
  uint4     q;
  _Float16  h[8];
  f16x8_t   v;
};

__device__ __forceinline__ uint32_t pk_bf16(float lo, float hi) {
  uint32_t d;
  asm("v_cvt_pk_bf16_f32 %0, %1, %2" : "=v"(d) : "v"(lo), "v"(hi));
  return d;
}

#define MFMA32H(a, b, c) __builtin_amdgcn_mfma_f32_32x32x16_f16(a, b, c, 0, 0, 0)
#define MFMA32B(a, b, c) __builtin_amdgcn_mfma_f32_32x32x16_bf16(a, b, c, 0, 0, 0)

// ---- device helpers (R6-validated bodies) ---------------------------------

__device__ __forceinline__ void prep_u_unit(const float* __restrict__ u,
                                            _Float16* __restrict__ uh, int t) {
  const int row = t >> 9;
  const int k8  = t & 511;
  const float4* p = (const float4*)(u + (size_t)row * D_DIM + (size_t)k8 * 8);
  const float4 a = p[0], b = p[1];
  FragH o;
  o.h[0] = (_Float16)a.x; o.h[1] = (_Float16)a.y;
  o.h[2] = (_Float16)a.z; o.h[3] = (_Float16)a.w;
  o.h[4] = (_Float16)b.x; o.h[5] = (_Float16)b.y;
  o.h[6] = (_Float16)b.z; o.h[7] = (_Float16)b.w;
  *(uint4*)(uh + (size_t)(k8 * C_DIM + row) * 8) = o.q;
}

__device__ __forceinline__ void prep_v_unit(const float* __restrict__ v,
                                            _Float16* __restrict__ vh, int t) {
  const float4* p = (const float4*)(v + (size_t)t * 8);
  const float4 a = p[0], b = p[1];
  FragH o;
  o.h[0] = (_Float16)a.x; o.h[1] = (_Float16)a.y;
  o.h[2] = (_Float16)a.z; o.h[3] = (_Float16)a.w;
  o.h[4] = (_Float16)b.x; o.h[5] = (_Float16)b.y;
  o.h[6] = (_Float16)b.z; o.h[7] = (_Float16)b.w;
  *(uint4*)(vh + (size_t)t * 8) = o.q;
}

// gram partial body: block (n,b), 4 waves, f16 datapath, depth-2 prefetch.
// Red must be the caller's 20 KB shared buffer. (R6-validated verbatim.)
__device__ __forceinline__ void gram_part_body(
    const _Float16* __restrict__ vh, const _Float16* __restrict__ uh,
    float* __restrict__ part, float (*Red)[C_DIM][20], int tid, int bid) {
  const int w   = tid >> 6;
  const int l   = tid & 63;
  const int n   = bid & 255;
  const int b   = bid >> 8;
  const int hg  = l >> 5;
  const int lm  = l & 31;
  const int kq  = b * KQB + w * KWV;

  f32x16_t acc[2][2];
#pragma unroll
  for (int a = 0; a < 2; ++a)
#pragma unroll
    for (int c = 0; c < 2; ++c)
#pragma unroll
      for (int i = 0; i < 16; ++i) acc[a][c][i] = 0.0f;

  const char* vg = (const char*)(vh + (size_t)n * D_DIM + kq) + hg * 16;
  const char* up = (const char*)uh +
                   ((size_t)(b * 128 + w * 32 + hg)) * 1024 + (size_t)lm * 16;

  FragH c0, c1, d0, d1;
  c0.q = *(const uint4*)(up);        c1.q = *(const uint4*)(up + 512);
  d0.q = *(const uint4*)(up + 2048); d1.q = *(const uint4*)(up + 2560);
  up += 4096;

#pragma unroll 2
  for (int s = 0; s < NSTEP; ++s) {
    FragH n0, n1;                    // tail over-reads into vh region (allocated)
    n0.q = *(const uint4*)(up);
    n1.q = *(const uint4*)(up + 512);
    up += 2048;
    FragH vv;
    vv.q = *(const uint4*)(vg + s * 32);
    FragH sa0, sa1;
    sa0.v = c0.v * vv.v;             // v_pk_mul_f16
    sa1.v = c1.v * vv.v;
    acc[0][0] = MFMA32H(sa0.v, c0.v, acc[0][0]);
    acc[0][1] = MFMA32H(sa0.v, c1.v, acc[0][1]);
    acc[1][0] = MFMA32H(sa1.v, c0.v, acc[1][0]);
    acc[1][1] = MFMA32H(sa1.v, c1.v, acc[1][1]);
    c0 = d0; c1 = d1; d0 = n0; d1 = n1;
  }

  float* slab = part + (size_t)(b * 256 + n) * 4096;
#pragma unroll
  for (int t = 0; t < 4; ++t) {
    __syncthreads();
    {
      const f32x16_t A = acc[t >> 1][t & 1];
      float* rp = &Red[w][l][0];
#pragma unroll
      for (int qq = 0; qq < 4; ++qq)
        *(float4*)(rp + qq * 4) =
            make_float4(A[qq * 4 + 0], A[qq * 4 + 1], A[qq * 4 + 2], A[qq * 4 + 3]);
    }
    __syncthreads();
    {
      const float4 r0 = *(const float4*)(&Red[0][l][w * 4]);
      const float4 r1 = *(const float4*)(&Red[1][l][w * 4]);
      const float4 r2 = *(const float4*)(&Red[2][l][w * 4]);
      const float4 r3 = *(const float4*)(&Red[3][l][w * 4]);
      const int tr = t >> 1, tc = t & 1;
      const int rbase = tr * 32 + w * 8 + ((l >> 5) << 2);
      const int col   = tc * 32 + (l & 31);
      float* op = slab + (size_t)rbase * 64 + col;
      op[0]   = r0.x + r1.x + r2.x + r3.x;
      op[64]  = r0.y + r1.y + r2.y + r3.y;
      op[128] = r0.z + r1.z + r2.z + r3.z;
      op[192] = r0.w + r1.w + r2.w + r3.w;
    }
  }
}

// ---- mega: everything in one cooperative dispatch -------------------------
__global__ __launch_bounds__(256, 4)
void mega_kernel(const float* __restrict__ v, const float* __restrict__ u,
                 _Float16* __restrict__ uh, _Float16* __restrict__ vh,
                 float* __restrict__ part, float* __restrict__ out)
{
  __shared__ float Red[4][C_DIM][20];
  const int bid = blockIdx.x;
  const int tid = threadIdx.x;
  const int gid = bid * 256 + tid;

  // phase 1: prep (blocks 0..127 -> u subtile; 128..639 -> v cast)
  if (bid < 128)      prep_u_unit(u, uh, gid);
  else if (bid < 640) prep_v_unit(v, vh, gid - 32768);

  cg::this_grid().sync();

  // phase 2: gram partials (all 1024 blocks)
  gram_part_body(vh, uh, part, Red, tid, bid);

  cg::this_grid().sync();

  // phase 3: sum 4 slabs -> out (coalesced float4 per thread)
  {
    const size_t i = (size_t)gid * 4;
    const float4 a = *(const float4*)(part + i);
    const float4 b = *(const float4*)(part + SLAB + i);
    const float4 c = *(const float4*)(part + 2 * (size_t)SLAB + i);
    const float4 d = *(const float4*)(part + 3 * (size_t)SLAB + i);
    *(float4*)(out + i) = make_float4(a.x + b.x + c.x + d.x,
                                      a.y + b.y + c.y + d.y,
                                      a.z + b.z + c.z + d.z,
                                      a.w + b.w + c.w + d.w);
  }
}

// ---- R6-validated standalone kernels (fallback path) ----------------------
__global__ __launch_bounds__(256) void prep_kernel(const float* __restrict__ u,
                                                   const float* __restrict__ v,
                                                   _Float16* __restrict__ uh,
                                                   _Float16* __restrict__ vh) {
  const int gid = blockIdx.x * 256 + threadIdx.x;
  if (blockIdx.x < 128) prep_u_unit(u, uh, gid);
  else                  prep_v_unit(v, vh, gid - 32768);
}

__global__ __launch_bounds__(256, 4)
void gram_part_kernel(const _Float16* __restrict__ vh,
                      const _Float16* __restrict__ uh,
                      float* __restrict__ part) {
  __shared__ float Red[4][C_DIM][20];
  gram_part_body(vh, uh, part, Red, threadIdx.x, blockIdx.x);
}

__global__ __launch_bounds__(256)
void reduce_kernel(const float* __restrict__ part, float* __restrict__ out) {
  const size_t i = ((size_t)blockIdx.x * 256 + threadIdx.x) * 4;
  const float4 a = *(const float4*)(part + i);
  const float4 b = *(const float4*)(part + SLAB + i);
  const float4 c = *(const float4*)(part + 2 * (size_t)SLAB + i);
  const float4 d = *(const float4*)(part + 3 * (size_t)SLAB + i);
  *(float4*)(out + i) = make_float4(a.x + b.x + c.x + d.x,
                                    a.y + b.y + c.y + d.y,
                                    a.z + b.z + c.z + d.z,
                                    a.w + b.w + c.w + d.w);
}

// ---- fallback (tiny ws): R5/R6-validated single-kernel bf16 path ----------
__global__ __launch_bounds__(256)
void gram_fallback_kernel(const float* __restrict__ vin,
                          const float* __restrict__ uf32,
                          float* __restrict__ out)
{
  __shared__ float Red[4][C_DIM][20];

  const int tid = threadIdx.x;
  const int w   = tid >> 6;
  const int l   = tid & 63;
  const int n   = blockIdx.x;
  const int hg  = l >> 5;
  const int lm  = l & 31;
  const int kq  = w * 1024;

  f32x16_t acc[2][2];
#pragma unroll
  for (int a = 0; a < 2; ++a)
#pragma unroll
    for (int c = 0; c < 2; ++c)
#pragma unroll
      for (int i = 0; i < 16; ++i) acc[a][c][i] = 0.0f;

  const char* vg  = (const char*)(vin + (size_t)n * D_DIM + kq) + hg * 32;
  const char* ua  = (const char*)(uf32 + (size_t)lm * D_DIM + kq) + hg * 32;
  const char* ubx = ua + (size_t)32 * D_DIM * 4;
  for (int s = 0; s < 64; ++s) {
    const float4 a0 = *(const float4*)(ua  + (size_t)s * 64);
    const float4 a1 = *(const float4*)(ua  + (size_t)s * 64 + 16);
    const float4 b0 = *(const float4*)(ubx + (size_t)s * 64);
    const float4 b1 = *(const float4*)(ubx + (size_t)s * 64 + 16);
    const float4 va = *(const float4*)(vg + s * 64);
    const float4 vb = *(const float4*)(vg + s * 64 + 16);
    Frag f0, f1, sa0, sa1;
    f0.u[0] = pk_bf16(a0.x, a0.y);  f0.u[1] = pk_bf16(a0.z, a0.w);
    f0.u[2] = pk_bf16(a1.x, a1.y);  f0.u[3] = pk_bf16(a1.z, a1.w);
    f1.u[0] = pk_bf16(b0.x, b0.y);  f1.u[1] = pk_bf16(b0.z, b0.w);
    f1.u[2] = pk_bf16(b1.x, b1.y);  f1.u[3] = pk_bf16(b1.z, b1.w);
    sa0.u[0] = pk_bf16(a0.x * va.x, a0.y * va.y);
    sa0.u[1] = pk_bf16(a0.z * va.z, a0.w * va.w);
    sa0.u[2] = pk_bf16(a1.x * vb.x, a1.y * vb.y);
    sa0.u[3] = pk_bf16(a1.z * vb.z, a1.w * vb.w);
    sa1.u[0] = pk_bf16(b0.x * va.x, b0.y * va.y);
    sa1.u[1] = pk_bf16(b0.z * va.z, b0.w * va.w);
    sa1.u[2] = pk_bf16(b1.x * vb.x, b1.y * vb.y);
    sa1.u[3] = pk_bf16(b1.z * vb.z, b1.w * vb.w);
    acc[0][0] = MFMA32B(sa0.b, f0.b, acc[0][0]);
    acc[0][1] = MFMA32B(sa0.b, f1.b, acc[0][1]);
    acc[1][0] = MFMA32B(sa1.b, f0.b, acc[1][0]);
    acc[1][1] = MFMA32B(sa1.b, f1.b, acc[1][1]);
  }

#pragma unroll
  for (int t = 0; t < 4; ++t) {
    __syncthreads();
    {
      const f32x16_t A = acc[t >> 1][t & 1];
      float* rp = &Red[w][l][0];
#pragma unroll
      for (int qq = 0; qq < 4; ++qq)
        *(float4*)(rp + qq * 4) =
            make_float4(A[qq * 4 + 0], A[qq * 4 + 1], A[qq * 4 + 2], A[qq * 4 + 3]);
    }
    __syncthreads();
    {
      const float4 r0 = *(const float4*)(&Red[0][l][w * 4]);
      const float4 r1 = *(const float4*)(&Red[1][l][w * 4]);
      const float4 r2 = *(const float4*)(&Red[2][l][w * 4]);
      const float4 r3 = *(const float4*)(&Red[3][l][w * 4]);
      const int tr = t >> 1, tc = t & 1;
      const int rbase = tr * 32 + w * 8 + ((l >> 5) << 2);
      const int col   = tc * 32 + (l & 31);
      float* op = out + (size_t)n * 4096 + (size_t)rbase * 64 + col;
      op[0]   = r0.x + r1.x + r2.x + r3.x;
      op[64]  = r0.y + r1.y + r2.y + r3.y;
      op[128] = r0.z + r1.z + r2.z + r3.z;
      op[192] = r0.w + r1.w + r2.w + r3.w;
    }
  }
}

extern "C" void kernel_launch(void* const* d_in, const int* in_sizes, int n_in,
                              void* d_out, int out_size, void* d_ws, size_t ws_size,
                              hipStream_t stream) {
  const float* v   = (const float*)d_in[0];
  const float* u   = (const float*)d_in[1];
  float*       out = (float*)d_out;
  if (ws_size >= ((size_t)20 << 20)) {
    _Float16* uh   = (_Float16*)d_ws;
    _Float16* vh   = (_Float16*)((char*)d_ws + VH_OFF);
    float*    part = (float*)((char*)d_ws + PART_OFF);
    void* args[] = {(void*)&v, (void*)&u, (void*)&uh, (void*)&vh,
                    (void*)&part, (void*)&out};
    hipError_t e = hipLaunchCooperativeKernel((const void*)mega_kernel,
                                              dim3(N_DIM * NQ), dim3(256),
                                              args, 0, stream);
    if (e != hipSuccess) {   // fallback: R6's validated 3-dispatch path
      prep_kernel<<<dim3(640), dim3(256), 0, stream>>>(u, v, uh, vh);
      gram_part_kernel<<<dim3(N_DIM * NQ), dim3(256), 0, stream>>>(vh, uh, part);
      reduce_kernel<<<dim3(SLAB / 4 / 256), dim3(256), 0, stream>>>(part, out);
    }
  } else {
    gram_fallback_kernel<<<dim3(N_DIM), dim3(256), 0, stream>>>(v, u, out);
  }
}

// Round 8
// 23.831 us; speedup vs baseline: 12.6644x; 12.6644x over previous
//
#include <hip/hip_runtime.h>
#include <stdint.h>

#define N_DIM 256
#define C_DIM 64
#define D_DIM 4096
#define NWAVE 8               // waves per block (K-split ways, in-block)
#define KWV   (D_DIM / NWAVE) // 512 k per wave
#define NSTEP (KWV / 16)      // 32 MFMA k-steps per wave

// ws layout: uh (f16 u, 512 KB) @0; vh (f16 v, 2 MB) @1MB
#define VH_OFF   (1u << 20)

typedef __bf16    bf16x8_t __attribute__((ext_vector_type(8)));
typedef _Float16  f16x8_t  __attribute__((ext_vector_type(8)));
typedef float     f32x16_t __attribute__((ext_vector_type(16)));

union Frag {
  uint4     q;
  uint32_t  u[4];
  bf16x8_t  b;
};
union FragH {
  uint4     q;
  _Float16  h[8];
  f16x8_t   v;
};

__device__ __forceinline__ uint32_t pk_bf16(float lo, float hi) {
  uint32_t d;
  asm("v_cvt_pk_bf16_f32 %0, %1, %2" : "=v"(d) : "v"(lo), "v"(hi));
  return d;
}

#define MFMA32H(a, b, c) __builtin_amdgcn_mfma_f32_32x32x16_f16(a, b, c, 0, 0, 0)
#define MFMA32B(a, b, c) __builtin_amdgcn_mfma_f32_32x32x16_bf16(a, b, c, 0, 0, 0)

// ---- prep helpers (R6-validated) ------------------------------------------
__device__ __forceinline__ void prep_u_unit(const float* __restrict__ u,
                                            _Float16* __restrict__ uh, int t) {
  const int row = t >> 9;
  const int k8  = t & 511;
  const float4* p = (const float4*)(u + (size_t)row * D_DIM + (size_t)k8 * 8);
  const float4 a = p[0], b = p[1];
  FragH o;
  o.h[0] = (_Float16)a.x; o.h[1] = (_Float16)a.y;
  o.h[2] = (_Float16)a.z; o.h[3] = (_Float16)a.w;
  o.h[4] = (_Float16)b.x; o.h[5] = (_Float16)b.y;
  o.h[6] = (_Float16)b.z; o.h[7] = (_Float16)b.w;
  *(uint4*)(uh + (size_t)(k8 * C_DIM + row) * 8) = o.q;
}

__device__ __forceinline__ void prep_v_unit(const float* __restrict__ v,
                                            _Float16* __restrict__ vh, int t) {
  const float4* p = (const float4*)(v + (size_t)t * 8);
  const float4 a = p[0], b = p[1];
  FragH o;
  o.h[0] = (_Float16)a.x; o.h[1] = (_Float16)a.y;
  o.h[2] = (_Float16)a.z; o.h[3] = (_Float16)a.w;
  o.h[4] = (_Float16)b.x; o.h[5] = (_Float16)b.y;
  o.h[6] = (_Float16)b.z; o.h[7] = (_Float16)b.w;
  *(uint4*)(vh + (size_t)t * 8) = o.q;
}

__global__ __launch_bounds__(256) void prep_kernel(const float* __restrict__ u,
                                                   const float* __restrict__ v,
                                                   _Float16* __restrict__ uh,
                                                   _Float16* __restrict__ vh) {
  const int gid = blockIdx.x * 256 + threadIdx.x;
  if (blockIdx.x < 128) prep_u_unit(u, uh, gid);
  else                  prep_v_unit(v, vh, gid - 32768);
}

// ---- gram: one 512-thread block per n; 8-way in-block K-split; direct out --
__global__ __launch_bounds__(512, 4)
void gram_kernel(const _Float16* __restrict__ vh,
                 const _Float16* __restrict__ uh,
                 float* __restrict__ out)
{
  __shared__ float Red[NWAVE][C_DIM][21];   // 43 KB; stride 21 -> bank-clean

  const int tid = threadIdx.x;
  const int w   = tid >> 6;      // wave id = K-segment (0..7)
  const int l   = tid & 63;
  const int n   = blockIdx.x;
  const int hg  = l >> 5;
  const int lm  = l & 31;

  f32x16_t acc[2][2];
#pragma unroll
  for (int a = 0; a < 2; ++a)
#pragma unroll
    for (int c = 0; c < 2; ++c)
#pragma unroll
      for (int i = 0; i < 16; ++i) acc[a][c][i] = 0.0f;

  // v: f16-packed broadcast loads (R6-validated pattern), wave's 1 KB slice
  const char* vg = (const char*)(vh + (size_t)n * D_DIM + w * KWV) + hg * 16;
  // u fragments: R6-validated subtile addressing, base unit = w*64 + hg
  const char* up = (const char*)uh + ((size_t)(w * 64 + hg)) * 1024 + (size_t)lm * 16;

  FragH c0, c1, d0, d1;
  c0.q = *(const uint4*)(up);        c1.q = *(const uint4*)(up + 512);
  d0.q = *(const uint4*)(up + 2048); d1.q = *(const uint4*)(up + 2560);
  up += 4096;

#pragma unroll 2
  for (int s = 0; s < NSTEP; ++s) {
    FragH n0, n1;          // depth-2 prefetch; tail over-reads pad before vh (allocated)
    n0.q = *(const uint4*)(up);
    n1.q = *(const uint4*)(up + 512);
    up += 2048;
    FragH vv;
    vv.q = *(const uint4*)(vg + s * 32);
    FragH sa0, sa1;
    sa0.v = c0.v * vv.v;   // v_pk_mul_f16
    sa1.v = c1.v * vv.v;
    acc[0][0] = MFMA32H(sa0.v, c0.v, acc[0][0]);
    acc[0][1] = MFMA32H(sa0.v, c1.v, acc[0][1]);
    acc[1][0] = MFMA32H(sa1.v, c0.v, acc[1][0]);
    acc[1][1] = MFMA32H(sa1.v, c1.v, acc[1][1]);
    c0 = d0; c1 = d1; d0 = n0; d1 = n1;
  }

  // ---- in-block K-reduction (8 partials) + direct out write ---------------
  // Producer (validated mapping): acc[tr][tc] reg j of lane (hg,lm) ->
  //   row = tr*32 + 4*hg + (j&3) + 8*(j>>2), col = tc*32 + lm.
  // Reader (w,l) handles j = 2w+q (q=0,1) for source-lane l, sums 8 waves.
  float* onb = out + (size_t)n * 4096;
#pragma unroll
  for (int t = 0; t < 4; ++t) {
    __syncthreads();                 // Red free for reuse
    {
      const f32x16_t A = acc[t >> 1][t & 1];
      float* rp = &Red[w][l][0];
#pragma unroll
      for (int j = 0; j < 16; ++j)
        rp[j] = A[j];
    }
    __syncthreads();                 // all partials visible
    {
      const int tr = t >> 1, tc = t & 1;
      const int col = tc * 32 + lm;
#pragma unroll
      for (int q = 0; q < 2; ++q) {
        const int j = 2 * w + q;
        float s = 0.0f;
#pragma unroll
        for (int ww = 0; ww < NWAVE; ++ww)
          s += Red[ww][l][j];
        const int row = tr * 32 + 4 * hg + (j & 3) + 8 * (j >> 2);
        onb[(size_t)row * 64 + col] = s;
      }
    }
  }
}

// ---- fallback (tiny ws): R5/R6-validated single-kernel bf16 path ----------
__global__ __launch_bounds__(256)
void gram_fallback_kernel(const float* __restrict__ vin,
                          const float* __restrict__ uf32,
                          float* __restrict__ out)
{
  __shared__ float Red[4][C_DIM][20];

  const int tid = threadIdx.x;
  const int w   = tid >> 6;
  const int l   = tid & 63;
  const int n   = blockIdx.x;
  const int hg  = l >> 5;
  const int lm  = l & 31;
  const int kq  = w * 1024;

  f32x16_t acc[2][2];
#pragma unroll
  for (int a = 0; a < 2; ++a)
#pragma unroll
    for (int c = 0; c < 2; ++c)
#pragma unroll
      for (int i = 0; i < 16; ++i) acc[a][c][i] = 0.0f;

  const char* vg  = (const char*)(vin + (size_t)n * D_DIM + kq) + hg * 32;
  const char* ua  = (const char*)(uf32 + (size_t)lm * D_DIM + kq) + hg * 32;
  const char* ubx = ua + (size_t)32 * D_DIM * 4;
  for (int s = 0; s < 64; ++s) {
    const float4 a0 = *(const float4*)(ua  + (size_t)s * 64);
    const float4 a1 = *(const float4*)(ua  + (size_t)s * 64 + 16);
    const float4 b0 = *(const float4*)(ubx + (size_t)s * 64);
    const float4 b1 = *(const float4*)(ubx + (size_t)s * 64 + 16);
    const float4 va = *(const float4*)(vg + s * 64);
    const float4 vb = *(const float4*)(vg + s * 64 + 16);
    Frag f0, f1, sa0, sa1;
    f0.u[0] = pk_bf16(a0.x, a0.y);  f0.u[1] = pk_bf16(a0.z, a0.w);
    f0.u[2] = pk_bf16(a1.x, a1.y);  f0.u[3] = pk_bf16(a1.z, a1.w);
    f1.u[0] = pk_bf16(b0.x, b0.y);  f1.u[1] = pk_bf16(b0.z, b0.w);
    f1.u[2] = pk_bf16(b1.x, b1.y);  f1.u[3] = pk_bf16(b1.z, b1.w);
    sa0.u[0] = pk_bf16(a0.x * va.x, a0.y * va.y);
    sa0.u[1] = pk_bf16(a0.z * va.z, a0.w * va.w);
    sa0.u[2] = pk_bf16(a1.x * vb.x, a1.y * vb.y);
    sa0.u[3] = pk_bf16(a1.z * vb.z, a1.w * vb.w);
    sa1.u[0] = pk_bf16(b0.x * va.x, b0.y * va.y);
    sa1.u[1] = pk_bf16(b0.z * va.z, b0.w * va.w);
    sa1.u[2] = pk_bf16(b1.x * vb.x, b1.y * vb.y);
    sa1.u[3] = pk_bf16(b1.z * vb.z, b1.w * vb.w);
    acc[0][0] = MFMA32B(sa0.b, f0.b, acc[0][0]);
    acc[0][1] = MFMA32B(sa0.b, f1.b, acc[0][1]);
    acc[1][0] = MFMA32B(sa1.b, f0.b, acc[1][0]);
    acc[1][1] = MFMA32B(sa1.b, f1.b, acc[1][1]);
  }

#pragma unroll
  for (int t = 0; t < 4; ++t) {
    __syncthreads();
    {
      const f32x16_t A = acc[t >> 1][t & 1];
      float* rp = &Red[w][l][0];
#pragma unroll
      for (int qq = 0; qq < 4; ++qq)
        *(float4*)(rp + qq * 4) =
            make_float4(A[qq * 4 + 0], A[qq * 4 + 1], A[qq * 4 + 2], A[qq * 4 + 3]);
    }
    __syncthreads();
    {
      const float4 r0 = *(const float4*)(&Red[0][l][w * 4]);
      const float4 r1 = *(const float4*)(&Red[1][l][w * 4]);
      const float4 r2 = *(const float4*)(&Red[2][l][w * 4]);
      const float4 r3 = *(const float4*)(&Red[3][l][w * 4]);
      const int tr = t >> 1, tc = t & 1;
      const int rbase = tr * 32 + w * 8 + ((l >> 5) << 2);
      const int col   = tc * 32 + (l & 31);
      float* op = out + (size_t)n * 4096 + (size_t)rbase * 64 + col;
      op[0]   = r0.x + r1.x + r2.x + r3.x;
      op[64]  = r0.y + r1.y + r2.y + r3.y;
      op[128] = r0.z + r1.z + r2.z + r3.z;
      op[192] = r0.w + r1.w + r2.w + r3.w;
    }
  }
}

extern "C" void kernel_launch(void* const* d_in, const int* in_sizes, int n_in,
                              void* d_out, int out_size, void* d_ws, size_t ws_size,
                              hipStream_t stream) {
  const float* v   = (const float*)d_in[0];
  const float* u   = (const float*)d_in[1];
  float*       out = (float*)d_out;
  if (ws_size >= ((size_t)4 << 20)) {
    _Float16* uh = (_Float16*)d_ws;
    _Float16* vh = (_Float16*)((char*)d_ws + VH_OFF);
    prep_kernel<<<dim3(640), dim3(256), 0, stream>>>(u, v, uh, vh);
    gram_kernel<<<dim3(N_DIM), dim3(512), 0, stream>>>(vh, uh, out);
  } else {
    gram_fallback_kernel<<<dim3(N_DIM), dim3(256), 0, stream>>>(v, u, out);
  }
}